// Round 3
// baseline (284.432 us; speedup 1.0000x reference)
//
#include <hip/hip_runtime.h>
#include <hip/hip_bf16.h>

#define D 128
#define HEADS 4
#define NEG_SLOPE 0.2f
#define QSCALE 0.0625f
#define QUNSCALE 16.0f

typedef __attribute__((ext_vector_type(8))) short short8;
typedef __attribute__((ext_vector_type(4))) float f32x4;
typedef __attribute__((ext_vector_type(2))) float f32x2;
typedef __attribute__((ext_vector_type(2))) _Float16 h2;

__device__ __forceinline__ float lrelu(float v) {
    return fmaxf(v, NEG_SLOPE * v);   // valid since NEG_SLOPE < 1
}

__device__ __forceinline__ short f2bf(float v) {
    __hip_bfloat16 b = __float2bfloat16(v);
    short s;
    __builtin_memcpy(&s, &b, 2);
    return s;
}

__device__ __forceinline__ unsigned short f2h(float v) {
    _Float16 h = (_Float16)v;
    unsigned short s;
    __builtin_memcpy(&s, &h, 2);
    return s;
}

// ------- W prep: combined [W | skip_W] -> bf16 transposed wsT[256][128] -----
// Also initializes the fixed-stride bucket cursors for binA.
#define BCAP 4608
__global__ __launch_bounds__(256)
void wprep_kernel(const float* __restrict__ W, const float* __restrict__ S,
                  short* __restrict__ wsT, int* __restrict__ woffA, int nb) {
    int idx = blockIdx.x * 256 + threadIdx.x;   // 32768
    int nn = idx >> 7, k = idx & 127;
    float v = (nn < 128) ? W[k * D + nn] : S[k * D + (nn - 128)];
    wsT[idx] = f2bf(v);
    if (idx < nb) woffA[idx] = idx * BCAP;
}

// ------- MFMA combined GEMM + fused attention projections -------------------
// Block: 64 rows x 256 combined cols, 8 waves of 32x64. H-half waves (wc<2)
// also reduce a_s/a_d from their fp32 acc fragments (head = col>>5).
// hb/baseb are stored as FP16 (packed math in gather).
#define LDSPAD 136
__global__ __launch_bounds__(512, 4)
void gemm_mfma_kernel(const float* __restrict__ x, const short* __restrict__ wsT,
                      const float* __restrict__ skip_b, const float* __restrict__ gat_bias,
                      const float* __restrict__ att_src, const float* __restrict__ att_dst,
                      unsigned short* __restrict__ hb, unsigned short* __restrict__ baseb,
                      float* __restrict__ a_s, float* __restrict__ a_d, int n) {
    __shared__ short xs[64][LDSPAD];
    const int t = threadIdx.x;
    const int row0 = blockIdx.x * 64;
    #pragma unroll
    for (int i = 0; i < 4; ++i) {
        int f = t + 512 * i;                 // 0..2047
        int row = f >> 5, c4 = (f & 31) * 4;
        float4 v = make_float4(0.f, 0.f, 0.f, 0.f);
        if (row0 + row < n) v = *(const float4*)&x[(size_t)(row0 + row) * D + c4];
        short4 s4;
        s4.x = f2bf(v.x); s4.y = f2bf(v.y); s4.z = f2bf(v.z); s4.w = f2bf(v.w);
        *(short4*)&xs[row][c4] = s4;
    }
    __syncthreads();
    const int wv = t >> 6, lane = t & 63;
    const int lo = lane & 15, hi = lane >> 4;
    const int wr = wv >> 2;
    const int wc = wv & 3;
    f32x4 acc[2][4] = {};
    #pragma unroll
    for (int k0 = 0; k0 < 128; k0 += 32) {
        const int kk = k0 + hi * 8;
        short8 a0 = *(const short8*)&xs[wr * 32 + lo][kk];
        short8 a1 = *(const short8*)&xs[wr * 32 + 16 + lo][kk];
        #pragma unroll
        for (int nt = 0; nt < 4; ++nt) {
            short8 b = *(const short8*)&wsT[(wc * 64 + nt * 16 + lo) * D + kk];
            acc[0][nt] = __builtin_amdgcn_mfma_f32_16x16x32_bf16(a0, b, acc[0][nt], 0, 0, 0);
            acc[1][nt] = __builtin_amdgcn_mfma_f32_16x16x32_bf16(a1, b, acc[1][nt], 0, 0, 0);
        }
    }
    // fused a_s/a_d for the H half (cols 0..127): head = col>>5
    if (wc < 2) {
        float as_[4], ad_[4];
        #pragma unroll
        for (int nt = 0; nt < 4; ++nt) {
            const int c = wc * 64 + nt * 16 + lo;
            as_[nt] = att_src[c];
            ad_[nt] = att_dst[c];
        }
        #pragma unroll
        for (int mt = 0; mt < 2; ++mt) {
            #pragma unroll
            for (int reg = 0; reg < 4; ++reg) {
                float ps0 = acc[mt][0][reg] * as_[0] + acc[mt][1][reg] * as_[1];
                float ps1 = acc[mt][2][reg] * as_[2] + acc[mt][3][reg] * as_[3];
                float pd0 = acc[mt][0][reg] * ad_[0] + acc[mt][1][reg] * ad_[1];
                float pd1 = acc[mt][2][reg] * ad_[2] + acc[mt][3][reg] * ad_[3];
                #pragma unroll
                for (int off = 1; off < 16; off <<= 1) {
                    ps0 += __shfl_xor(ps0, off, 64);
                    ps1 += __shfl_xor(ps1, off, 64);
                    pd0 += __shfl_xor(pd0, off, 64);
                    pd1 += __shfl_xor(pd1, off, 64);
                }
                if (lo == 0) {
                    const int r = row0 + wr * 32 + mt * 16 + hi * 4 + reg;
                    if (r < n) {
                        a_s[r * HEADS + wc * 2 + 0] = ps0;
                        a_s[r * HEADS + wc * 2 + 1] = ps1;
                        a_d[r * HEADS + wc * 2 + 0] = pd0;
                        a_d[r * HEADS + wc * 2 + 1] = pd1;
                    }
                }
            }
        }
    }
    // epilogue: C/D layout col=lane&15, row=(lane>>4)*4+reg  (stores FP16)
    #pragma unroll
    for (int nt = 0; nt < 4; ++nt) {
        const int cc = wc * 64 + nt * 16 + lo;
        const bool isH = cc < 128;
        const float bb = isH ? 0.f : (skip_b[cc - 128] + gat_bias[cc - 128]);
        unsigned short* dst = isH ? hb : baseb;
        const int c = isH ? cc : cc - 128;
        #pragma unroll
        for (int mt = 0; mt < 2; ++mt) {
            const int rbase = row0 + wr * 32 + mt * 16 + hi * 4;
            #pragma unroll
            for (int reg = 0; reg < 4; ++reg) {
                const int r = rbase + reg;
                if (r < n) dst[(size_t)r * D + c] = f2h(acc[mt][nt][reg] + bb);
            }
        }
    }
}

// ================= One-pass bucketed scatter (fixed-stride buckets) =========
// pairs packed 32-bit: (src << 8) | (dst & 255)
#define BEPT 16
#define BCHUNK (256 * BEPT)

__global__ __launch_bounds__(256)
void binA_kernel(const int* __restrict__ ei, int* __restrict__ woffA,
                 unsigned int* __restrict__ pairs, int E_, int nb) {
    __shared__ int hist[512];
    __shared__ int gbase[512];
    const int t = threadIdx.x;
    for (int q = t; q < 512; q += 256) hist[q] = 0;
    __syncthreads();
    int sv[BEPT], dv[BEPT], rk[BEPT];
    const int base = blockIdx.x * BCHUNK;
    #pragma unroll
    for (int i = 0; i < BEPT; ++i) {
        int e = base + i * 256 + t;
        if (e < E_) {
            sv[i] = ei[e];
            dv[i] = ei[E_ + e];
            rk[i] = atomicAdd(&hist[dv[i] >> 8], 1);
        } else {
            sv[i] = -1;
        }
    }
    __syncthreads();
    for (int q = t; q < nb; q += 256) {
        int v = hist[q];
        gbase[q] = v ? atomicAdd(&woffA[q], v) : 0;
    }
    __syncthreads();
    #pragma unroll
    for (int i = 0; i < BEPT; ++i) {
        if (sv[i] >= 0) {
            int pos = gbase[dv[i] >> 8] + rk[i];
            pairs[pos] = ((unsigned int)sv[i] << 8) | (unsigned int)(dv[i] & 255);
        }
    }
}

// ---- pass B: one block per bucket; single pass, edges cached in registers --
#define KCAP 24
__global__ __launch_bounds__(256)
void binB_kernel(const unsigned int* __restrict__ pairs, const int* __restrict__ wcur,
                 int* __restrict__ cnt, int* __restrict__ offs,
                 int* __restrict__ ssrc, int n) {
    __shared__ int nhist[256];
    __shared__ int sc[256];
    __shared__ int nbase[256];
    const int b = blockIdx.x;
    const int t = threadIdx.x;
    const int node0 = b << 8;
    const int sbeg = b * BCAP, send = wcur[b];
    nhist[t] = 0;
    __syncthreads();
    unsigned int pk[KCAP];
    int rk[KCAP];
    int nl = 0;
    for (int e = sbeg + t; e < send; e += 256) {
        unsigned int p = pairs[e];
        int r = atomicAdd(&nhist[p & 255], 1);
        if (nl < KCAP) { pk[nl] = p; rk[nl] = r; }
        ++nl;
    }
    __syncthreads();
    int v = nhist[t];
    sc[t] = v;
    __syncthreads();
    for (int off = 1; off < 256; off <<= 1) {
        int x = (t >= off) ? sc[t - off] : 0;
        __syncthreads();
        sc[t] += x;
        __syncthreads();
    }
    int ex = sc[t] - v;
    nbase[t] = sbeg + ex;
    if (node0 + t < n) {
        cnt[node0 + t] = v;
        offs[node0 + t] = sbeg + ex;
    }
    __syncthreads();
    const int m = nl < KCAP ? nl : KCAP;
    for (int i = 0; i < m; ++i) {
        int pos = nbase[pk[i] & 255] + rk[i];
        ssrc[pos] = (int)(pk[i] >> 8);
    }
}

// ---------------- Gather: wave/node; 16 lanes/edge, uint4 rows --------------
// lane layout: l15 = lane&15 (channel group: channels l15*8..+7, head=l15>>2),
//              grp = lane>>4 (edge slot within quad).
// One global_load_dwordx4 covers 4 edges per wave; 2 bpermutes per 4 edges.
__global__ __launch_bounds__(256)
void gather_kernel(const int* __restrict__ offs, const int* __restrict__ cnt,
                   const int* __restrict__ ssrc, const float* __restrict__ a_s,
                   const float* __restrict__ a_d, const uint4* __restrict__ hb16,
                   const uint4* __restrict__ baseb16,
                   const float* __restrict__ ln_g, const float* __restrict__ ln_b,
                   float* __restrict__ out, int n) {
    const int lane = threadIdx.x & 63;
    const int i = blockIdx.x * 4 + (threadIdx.x >> 6);
    if (i >= n) return;
    const int e4 = lane >> 2, h4 = lane & 3;
    const int l15 = lane & 15;
    const int grp = lane >> 4;
    const int hh = l15 >> 2;              // head of this lane's 8 channels
    // prefetch tail operands off the critical path
    const uint4 bv = baseb16[(size_t)i * 16 + l15];
    const float2 g2 = ((const float2*)ln_g)[l15 * 4 + grp];
    const float2 lb2 = ((const float2*)ln_b)[l15 * 4 + grp];
    const float as_h4 = a_s[i * HEADS + h4];
    const float ad_h4 = a_d[i * HEADS + h4];
    const float qself = __expf(lrelu(as_h4 + ad_h4));
    float zacc = (e4 == 0) ? qself : 0.f;
    h2 acc0 = {0.f, 0.f}, acc1 = {0.f, 0.f}, acc2 = {0.f, 0.f}, acc3 = {0.f, 0.f};
    {
        const float qs = __shfl(qself, hh, 64) * QSCALE;
        if (grp == 0) {
            const uint4 u = hb16[(size_t)i * 16 + l15];
            const _Float16 wh = (_Float16)qs;
            const h2 w2 = {wh, wh};
            acc0 = __builtin_bit_cast(h2, u.x) * w2;
            acc1 = __builtin_bit_cast(h2, u.y) * w2;
            acc2 = __builtin_bit_cast(h2, u.z) * w2;
            acc3 = __builtin_bit_cast(h2, u.w) * w2;
        }
    }
    const int o = offs[i];
    const int c = cnt[i];
    for (int k0 = 0; k0 < c; k0 += 16) {
        const int rem = c - k0;
        int srow = 0;
        float q = 0.f;
        if (e4 < rem) {
            const int sidx = ssrc[o + k0 + e4];
            srow = sidx << 4;
            q = __expf(lrelu(a_s[sidx * HEADS + h4] + ad_h4));
        }
        zacc += q;
        const _Float16 qh = (_Float16)(q * QSCALE);
        const h2 qv = {qh, qh};
        const int qpk = __builtin_bit_cast(int, qv);
        const int m = rem < 16 ? rem : 16;
        int ee = 0;
        for (; ee + 8 <= m; ee += 8) {
            const int slA = (ee + grp) << 2;
            const int slB = (ee + 4 + grp) << 2;
            const int rA = __shfl(srow, slA, 64) + l15;
            const int rB = __shfl(srow, slB, 64) + l15;
            const h2 qA = __builtin_bit_cast(h2, __shfl(qpk, slA + hh, 64));
            const h2 qB = __builtin_bit_cast(h2, __shfl(qpk, slB + hh, 64));
            const uint4 uA = hb16[(size_t)(unsigned)rA];
            const uint4 uB = hb16[(size_t)(unsigned)rB];
            acc0 += __builtin_bit_cast(h2, uA.x) * qA;
            acc1 += __builtin_bit_cast(h2, uA.y) * qA;
            acc2 += __builtin_bit_cast(h2, uA.z) * qA;
            acc3 += __builtin_bit_cast(h2, uA.w) * qA;
            acc0 += __builtin_bit_cast(h2, uB.x) * qB;
            acc1 += __builtin_bit_cast(h2, uB.y) * qB;
            acc2 += __builtin_bit_cast(h2, uB.z) * qB;
            acc3 += __builtin_bit_cast(h2, uB.w) * qB;
        }
        for (; ee < m; ee += 4) {
            const int slot = ee + grp;
            const int sl = slot << 2;
            const int rA = __shfl(srow, sl, 64) + l15;
            const h2 qA = __builtin_bit_cast(h2, __shfl(qpk, sl + hh, 64));
            if (slot < m) {
                const uint4 uA = hb16[(size_t)(unsigned)rA];
                acc0 += __builtin_bit_cast(h2, uA.x) * qA;
                acc1 += __builtin_bit_cast(h2, uA.y) * qA;
                acc2 += __builtin_bit_cast(h2, uA.z) * qA;
                acc3 += __builtin_bit_cast(h2, uA.w) * qA;
            }
        }
    }
    // merge the 4 edge-slot groups (packed fp16 adds)
    #pragma unroll
    for (int off = 16; off < 64; off <<= 1) {
        acc0 += __builtin_bit_cast(h2, __shfl_xor(__builtin_bit_cast(int, acc0), off, 64));
        acc1 += __builtin_bit_cast(h2, __shfl_xor(__builtin_bit_cast(int, acc1), off, 64));
        acc2 += __builtin_bit_cast(h2, __shfl_xor(__builtin_bit_cast(int, acc2), off, 64));
        acc3 += __builtin_bit_cast(h2, __shfl_xor(__builtin_bit_cast(int, acc3), off, 64));
    }
    #pragma unroll
    for (int off = 4; off < 64; off <<= 1) zacc += __shfl_xor(zacc, off, 64);
    const float zz = __shfl(zacc, hh, 64);
    const float rz = QUNSCALE / (zz + 1e-16f);
    const h2 b0 = __builtin_bit_cast(h2, bv.x);
    const h2 b1 = __builtin_bit_cast(h2, bv.y);
    const h2 b2 = __builtin_bit_cast(h2, bv.z);
    const h2 b3 = __builtin_bit_cast(h2, bv.w);
    const float v0 = (float)acc0.x * rz + (float)b0.x;
    const float v1 = (float)acc0.y * rz + (float)b0.y;
    const float v2 = (float)acc1.x * rz + (float)b1.x;
    const float v3 = (float)acc1.y * rz + (float)b1.y;
    const float v4 = (float)acc2.x * rz + (float)b2.x;
    const float v5 = (float)acc2.y * rz + (float)b2.y;
    const float v6 = (float)acc3.x * rz + (float)b3.x;
    const float v7 = (float)acc3.y * rz + (float)b3.y;
    float s1 = v0 + v1 + v2 + v3 + v4 + v5 + v6 + v7;
    float s2 = v0 * v0 + v1 * v1 + v2 * v2 + v3 * v3
             + v4 * v4 + v5 * v5 + v6 * v6 + v7 * v7;
    #pragma unroll
    for (int off = 1; off < 16; off <<= 1) {
        s1 += __shfl_xor(s1, off, 64);
        s2 += __shfl_xor(s2, off, 64);
    }
    const float mu = s1 * (1.f / 128.f);
    const float var = s2 * (1.f / 128.f) - mu * mu;
    const float r = rsqrtf(var + 1e-5f);
    const float lo = grp == 0 ? v0 : grp == 1 ? v2 : grp == 2 ? v4 : v6;
    const float hi = grp == 0 ? v1 : grp == 1 ? v3 : grp == 2 ? v5 : v7;
    f32x2 o2;
    o2.x = (lo - mu) * r * g2.x + lb2.x;
    o2.y = (hi - mu) * r * g2.y + lb2.y;
    __builtin_nontemporal_store(o2, (f32x2*)out + ((size_t)i * 64 + l15 * 4 + grp));
}

extern "C" void kernel_launch(void* const* d_in, const int* in_sizes, int n_in,
                              void* d_out, int out_size, void* d_ws, size_t ws_size,
                              hipStream_t stream) {
    const float* x        = (const float*)d_in[0];
    const int*   ei       = (const int*)d_in[1];
    const float* W        = (const float*)d_in[2];
    const float* att_src  = (const float*)d_in[3];
    const float* att_dst  = (const float*)d_in[4];
    const float* gat_bias = (const float*)d_in[5];
    const float* skip_W   = (const float*)d_in[6];
    const float* skip_b   = (const float*)d_in[7];
    const float* ln_g     = (const float*)d_in[8];
    const float* ln_b     = (const float*)d_in[9];
    float* out = (float*)d_out;

    const int n  = in_sizes[0] / D;   // 100000
    const int E_ = in_sizes[1] / 2;   // 1600000
    const int nb = (n + 255) >> 8;

    char* p = (char*)d_ws;
    auto carve = [&p](size_t bytes) {
        char* r = p;
        p += (bytes + 255) & ~(size_t)255;
        return r;
    };
    short* wsT            = (short*)carve(32768 * sizeof(short));
    unsigned short* hb    = (unsigned short*)carve((size_t)n * D * 2);
    unsigned short* baseb = (unsigned short*)carve((size_t)n * D * 2);
    float* a_s            = (float*)carve((size_t)n * HEADS * 4);
    float* a_d            = (float*)carve((size_t)n * HEADS * 4);
    int*   cnt            = (int*)carve((size_t)n * 4);
    int*   offs           = (int*)carve((size_t)n * 4);
    int*   woffA          = (int*)carve(512 * 4);
    int*   ssrc           = (int*)carve((size_t)nb * BCAP * 4);
    unsigned int* pairs   = (unsigned int*)carve((size_t)nb * BCAP * 4);

    wprep_kernel<<<128, 256, 0, stream>>>(W, skip_W, wsT, woffA, nb);
    gemm_mfma_kernel<<<(n + 63) / 64, 512, 0, stream>>>(x, wsT, skip_b, gat_bias,
                                                        att_src, att_dst,
                                                        hb, baseb, a_s, a_d, n);
    const int BA = (E_ + BCHUNK - 1) / BCHUNK;
    binA_kernel<<<BA, 256, 0, stream>>>(ei, woffA, pairs, E_, nb);
    binB_kernel<<<nb, 256, 0, stream>>>(pairs, woffA, cnt, offs, ssrc, n);
    gather_kernel<<<(n + 3) / 4, 256, 0, stream>>>(offs, cnt, ssrc, a_s, a_d,
                                                   (const uint4*)hb,
                                                   (const uint4*)baseb,
                                                   ln_g, ln_b, out, n);
}

// Round 4
// 281.778 us; speedup vs baseline: 1.0094x; 1.0094x over previous
//
#include <hip/hip_runtime.h>
#include <hip/hip_bf16.h>

#define D 128
#define HEADS 4
#define NEG_SLOPE 0.2f
#define QSCALE 0.0625f
#define QUNSCALE 16.0f

typedef __attribute__((ext_vector_type(8))) short short8;
typedef __attribute__((ext_vector_type(4))) float f32x4;
typedef __attribute__((ext_vector_type(2))) float f32x2;
typedef __attribute__((ext_vector_type(2))) _Float16 h2;

__device__ __forceinline__ float lrelu(float v) {
    return fmaxf(v, NEG_SLOPE * v);   // valid since NEG_SLOPE < 1
}

__device__ __forceinline__ short f2bf(float v) {
    __hip_bfloat16 b = __float2bfloat16(v);
    short s;
    __builtin_memcpy(&s, &b, 2);
    return s;
}

__device__ __forceinline__ unsigned short f2h(float v) {
    _Float16 h = (_Float16)v;
    unsigned short s;
    __builtin_memcpy(&s, &h, 2);
    return s;
}

// ------- W prep: combined [W | skip_W] -> bf16 transposed wsT[256][128] -----
// Also initializes the fixed-stride bucket cursors for binA.
#define BCAP 4608
__global__ __launch_bounds__(256)
void wprep_kernel(const float* __restrict__ W, const float* __restrict__ S,
                  short* __restrict__ wsT, int* __restrict__ woffA, int nb) {
    int idx = blockIdx.x * 256 + threadIdx.x;   // 32768
    int nn = idx >> 7, k = idx & 127;
    float v = (nn < 128) ? W[k * D + nn] : S[k * D + (nn - 128)];
    wsT[idx] = f2bf(v);
    if (idx < nb) woffA[idx] = idx * BCAP;
}

// ------- MFMA combined GEMM + fused attention projections -------------------
#define LDSPAD 136
__global__ __launch_bounds__(512, 4)
void gemm_mfma_kernel(const float* __restrict__ x, const short* __restrict__ wsT,
                      const float* __restrict__ skip_b, const float* __restrict__ gat_bias,
                      const float* __restrict__ att_src, const float* __restrict__ att_dst,
                      unsigned short* __restrict__ hb, unsigned short* __restrict__ baseb,
                      float* __restrict__ a_s, float* __restrict__ a_d, int n) {
    __shared__ short xs[64][LDSPAD];
    const int t = threadIdx.x;
    const int row0 = blockIdx.x * 64;
    #pragma unroll
    for (int i = 0; i < 4; ++i) {
        int f = t + 512 * i;                 // 0..2047
        int row = f >> 5, c4 = (f & 31) * 4;
        float4 v = make_float4(0.f, 0.f, 0.f, 0.f);
        if (row0 + row < n) v = *(const float4*)&x[(size_t)(row0 + row) * D + c4];
        short4 s4;
        s4.x = f2bf(v.x); s4.y = f2bf(v.y); s4.z = f2bf(v.z); s4.w = f2bf(v.w);
        *(short4*)&xs[row][c4] = s4;
    }
    __syncthreads();
    const int wv = t >> 6, lane = t & 63;
    const int lo = lane & 15, hi = lane >> 4;
    const int wr = wv >> 2;
    const int wc = wv & 3;
    f32x4 acc[2][4] = {};
    #pragma unroll
    for (int k0 = 0; k0 < 128; k0 += 32) {
        const int kk = k0 + hi * 8;
        short8 a0 = *(const short8*)&xs[wr * 32 + lo][kk];
        short8 a1 = *(const short8*)&xs[wr * 32 + 16 + lo][kk];
        #pragma unroll
        for (int nt = 0; nt < 4; ++nt) {
            short8 b = *(const short8*)&wsT[(wc * 64 + nt * 16 + lo) * D + kk];
            acc[0][nt] = __builtin_amdgcn_mfma_f32_16x16x32_bf16(a0, b, acc[0][nt], 0, 0, 0);
            acc[1][nt] = __builtin_amdgcn_mfma_f32_16x16x32_bf16(a1, b, acc[1][nt], 0, 0, 0);
        }
    }
    // fused a_s/a_d for the H half (cols 0..127): head = col>>5
    if (wc < 2) {
        float as_[4], ad_[4];
        #pragma unroll
        for (int nt = 0; nt < 4; ++nt) {
            const int c = wc * 64 + nt * 16 + lo;
            as_[nt] = att_src[c];
            ad_[nt] = att_dst[c];
        }
        #pragma unroll
        for (int mt = 0; mt < 2; ++mt) {
            #pragma unroll
            for (int reg = 0; reg < 4; ++reg) {
                float ps0 = acc[mt][0][reg] * as_[0] + acc[mt][1][reg] * as_[1];
                float ps1 = acc[mt][2][reg] * as_[2] + acc[mt][3][reg] * as_[3];
                float pd0 = acc[mt][0][reg] * ad_[0] + acc[mt][1][reg] * ad_[1];
                float pd1 = acc[mt][2][reg] * ad_[2] + acc[mt][3][reg] * ad_[3];
                #pragma unroll
                for (int off = 1; off < 16; off <<= 1) {
                    ps0 += __shfl_xor(ps0, off, 64);
                    ps1 += __shfl_xor(ps1, off, 64);
                    pd0 += __shfl_xor(pd0, off, 64);
                    pd1 += __shfl_xor(pd1, off, 64);
                }
                if (lo == 0) {
                    const int r = row0 + wr * 32 + mt * 16 + hi * 4 + reg;
                    if (r < n) {
                        a_s[r * HEADS + wc * 2 + 0] = ps0;
                        a_s[r * HEADS + wc * 2 + 1] = ps1;
                        a_d[r * HEADS + wc * 2 + 0] = pd0;
                        a_d[r * HEADS + wc * 2 + 1] = pd1;
                    }
                }
            }
        }
    }
    // epilogue: C/D layout col=lane&15, row=(lane>>4)*4+reg  (stores FP16)
    #pragma unroll
    for (int nt = 0; nt < 4; ++nt) {
        const int cc = wc * 64 + nt * 16 + lo;
        const bool isH = cc < 128;
        const float bb = isH ? 0.f : (skip_b[cc - 128] + gat_bias[cc - 128]);
        unsigned short* dst = isH ? hb : baseb;
        const int c = isH ? cc : cc - 128;
        #pragma unroll
        for (int mt = 0; mt < 2; ++mt) {
            const int rbase = row0 + wr * 32 + mt * 16 + hi * 4;
            #pragma unroll
            for (int reg = 0; reg < 4; ++reg) {
                const int r = rbase + reg;
                if (r < n) dst[(size_t)r * D + c] = f2h(acc[mt][nt][reg] + bb);
            }
        }
    }
}

// ================= One-pass bucketed sort, LDS-staged coalesced writes ======
// pairs packed 32-bit: (src << 8) | (dst & 255)
#define BEPT 16
#define BCHUNK (256 * BEPT)

__global__ __launch_bounds__(256)
void binA_kernel(const int* __restrict__ ei, int* __restrict__ woffA,
                 unsigned int* __restrict__ pairs, int E_, int nb) {
    __shared__ int hist[512];
    __shared__ int lbase[512];
    __shared__ int gbase[512];
    __shared__ int ts[256];
    __shared__ unsigned int lp[BCHUNK];      // locally bucket-sorted pairs
    __shared__ unsigned short lq[BCHUNK];    // bucket id per sorted slot
    const int t = threadIdx.x;
    for (int q = t; q < 512; q += 256) hist[q] = 0;
    __syncthreads();
    int sv[BEPT], dv[BEPT], rk[BEPT];
    const int base = blockIdx.x * BCHUNK;
    #pragma unroll
    for (int i = 0; i < BEPT; ++i) {
        int e = base + i * 256 + t;
        if (e < E_) {
            sv[i] = ei[e];
            dv[i] = ei[E_ + e];
            rk[i] = atomicAdd(&hist[dv[i] >> 8], 1);
        } else {
            sv[i] = -1;
        }
    }
    __syncthreads();
    // exclusive scan over 512 buckets (2 per thread)
    const int h0 = hist[2 * t], h1 = hist[2 * t + 1];
    ts[t] = h0 + h1;
    __syncthreads();
    for (int off = 1; off < 256; off <<= 1) {
        int x = (t >= off) ? ts[t - off] : 0;
        __syncthreads();
        ts[t] += x;
        __syncthreads();
    }
    const int pb = ts[t] - h0 - h1;
    lbase[2 * t] = pb;
    lbase[2 * t + 1] = pb + h0;
    // grab one global chunk per non-empty bucket
    for (int q = t; q < nb; q += 256) {
        int v = hist[q];
        gbase[q] = v ? atomicAdd(&woffA[q], v) : 0;
    }
    __syncthreads();
    const int total = ts[255];
    // LDS scatter into bucket-sorted order
    #pragma unroll
    for (int i = 0; i < BEPT; ++i) {
        if (sv[i] >= 0) {
            const int q = dv[i] >> 8;
            const int pos = lbase[q] + rk[i];
            lp[pos] = ((unsigned int)sv[i] << 8) | (unsigned int)(dv[i] & 255);
            lq[pos] = (unsigned short)q;
        }
    }
    __syncthreads();
    // coalesced-run flush: consecutive i within a bucket -> consecutive addrs
    for (int i = t; i < total; i += 256) {
        const int q = lq[i];
        pairs[gbase[q] + (i - lbase[q])] = lp[i];
    }
}

// ---- pass B: one block per bucket; LDS full sort, streaming ssrc write -----
#define KCAP 24
__global__ __launch_bounds__(256)
void binB_kernel(const unsigned int* __restrict__ pairs, const int* __restrict__ wcur,
                 int* __restrict__ cnt, int* __restrict__ offs,
                 int* __restrict__ ssrc, int n) {
    __shared__ int nhist[256];
    __shared__ int sc[256];
    __shared__ int sorted[BCAP];
    const int b = blockIdx.x;
    const int t = threadIdx.x;
    const int node0 = b << 8;
    const int sbeg = b * BCAP;
    int send = wcur[b];
    if (send > sbeg + BCAP) send = sbeg + BCAP;   // safety clamp
    const int total = send - sbeg;
    nhist[t] = 0;
    __syncthreads();
    unsigned int pk[KCAP];
    int rk[KCAP];
    int nl = 0;
    for (int e = sbeg + t; e < send; e += 256) {
        unsigned int p = pairs[e];
        int r = atomicAdd(&nhist[p & 255], 1);
        if (nl < KCAP) { pk[nl] = p; rk[nl] = r; }
        ++nl;
    }
    __syncthreads();
    const int v = nhist[t];
    sc[t] = v;
    __syncthreads();
    for (int off = 1; off < 256; off <<= 1) {
        int x = (t >= off) ? sc[t - off] : 0;
        __syncthreads();
        sc[t] += x;
        __syncthreads();
    }
    const int ex = sc[t] - v;
    if (node0 + t < n) {
        cnt[node0 + t] = v;
        offs[node0 + t] = sbeg + ex;
    }
    __syncthreads();
    nhist[t] = ex;                 // reuse as per-node local base
    __syncthreads();
    const int m = nl < KCAP ? nl : KCAP;
    for (int i = 0; i < m; ++i) {
        sorted[nhist[pk[i] & 255] + rk[i]] = (int)(pk[i] >> 8);
    }
    __syncthreads();
    // perfectly coalesced streaming write of the sorted bucket
    for (int i = t; i < total; i += 256) ssrc[sbeg + i] = sorted[i];
}

// ---------------- Gather: wave/node; 16 lanes/edge, uint4 rows --------------
__global__ __launch_bounds__(256)
void gather_kernel(const int* __restrict__ offs, const int* __restrict__ cnt,
                   const int* __restrict__ ssrc, const float* __restrict__ a_s,
                   const float* __restrict__ a_d, const uint4* __restrict__ hb16,
                   const uint4* __restrict__ baseb16,
                   const float* __restrict__ ln_g, const float* __restrict__ ln_b,
                   float* __restrict__ out, int n) {
    const int lane = threadIdx.x & 63;
    const int i = blockIdx.x * 4 + (threadIdx.x >> 6);
    if (i >= n) return;
    const int e4 = lane >> 2, h4 = lane & 3;
    const int l15 = lane & 15;
    const int grp = lane >> 4;
    const int hh = l15 >> 2;              // head of this lane's 8 channels
    // prefetch tail operands off the critical path
    const uint4 bv = baseb16[(size_t)i * 16 + l15];
    const float2 g2 = ((const float2*)ln_g)[l15 * 4 + grp];
    const float2 lb2 = ((const float2*)ln_b)[l15 * 4 + grp];
    const float as_h4 = a_s[i * HEADS + h4];
    const float ad_h4 = a_d[i * HEADS + h4];
    const float qself = __expf(lrelu(as_h4 + ad_h4));
    float zacc = (e4 == 0) ? qself : 0.f;
    h2 acc0 = {0.f, 0.f}, acc1 = {0.f, 0.f}, acc2 = {0.f, 0.f}, acc3 = {0.f, 0.f};
    {
        const float qs = __shfl(qself, hh, 64) * QSCALE;
        if (grp == 0) {
            const uint4 u = hb16[(size_t)i * 16 + l15];
            const _Float16 wh = (_Float16)qs;
            const h2 w2 = {wh, wh};
            acc0 = __builtin_bit_cast(h2, u.x) * w2;
            acc1 = __builtin_bit_cast(h2, u.y) * w2;
            acc2 = __builtin_bit_cast(h2, u.z) * w2;
            acc3 = __builtin_bit_cast(h2, u.w) * w2;
        }
    }
    const int o = offs[i];
    const int c = cnt[i];
    for (int k0 = 0; k0 < c; k0 += 16) {
        const int rem = c - k0;
        int srow = 0;
        float q = 0.f;
        if (e4 < rem) {
            const int sidx = ssrc[o + k0 + e4];
            srow = sidx << 4;
            q = __expf(lrelu(a_s[sidx * HEADS + h4] + ad_h4));
        }
        zacc += q;
        const _Float16 qh = (_Float16)(q * QSCALE);
        const h2 qv = {qh, qh};
        const int qpk = __builtin_bit_cast(int, qv);
        const int m = rem < 16 ? rem : 16;
        int ee = 0;
        for (; ee + 8 <= m; ee += 8) {
            const int slA = (ee + grp) << 2;
            const int slB = (ee + 4 + grp) << 2;
            const int rA = __shfl(srow, slA, 64) + l15;
            const int rB = __shfl(srow, slB, 64) + l15;
            const h2 qA = __builtin_bit_cast(h2, __shfl(qpk, slA + hh, 64));
            const h2 qB = __builtin_bit_cast(h2, __shfl(qpk, slB + hh, 64));
            const uint4 uA = hb16[(size_t)(unsigned)rA];
            const uint4 uB = hb16[(size_t)(unsigned)rB];
            acc0 += __builtin_bit_cast(h2, uA.x) * qA;
            acc1 += __builtin_bit_cast(h2, uA.y) * qA;
            acc2 += __builtin_bit_cast(h2, uA.z) * qA;
            acc3 += __builtin_bit_cast(h2, uA.w) * qA;
            acc0 += __builtin_bit_cast(h2, uB.x) * qB;
            acc1 += __builtin_bit_cast(h2, uB.y) * qB;
            acc2 += __builtin_bit_cast(h2, uB.z) * qB;
            acc3 += __builtin_bit_cast(h2, uB.w) * qB;
        }
        for (; ee < m; ee += 4) {
            const int slot = ee + grp;
            const int sl = slot << 2;
            const int rA = __shfl(srow, sl, 64) + l15;
            const h2 qA = __builtin_bit_cast(h2, __shfl(qpk, sl + hh, 64));
            if (slot < m) {
                const uint4 uA = hb16[(size_t)(unsigned)rA];
                acc0 += __builtin_bit_cast(h2, uA.x) * qA;
                acc1 += __builtin_bit_cast(h2, uA.y) * qA;
                acc2 += __builtin_bit_cast(h2, uA.z) * qA;
                acc3 += __builtin_bit_cast(h2, uA.w) * qA;
            }
        }
    }
    // merge the 4 edge-slot groups (packed fp16 adds)
    #pragma unroll
    for (int off = 16; off < 64; off <<= 1) {
        acc0 += __builtin_bit_cast(h2, __shfl_xor(__builtin_bit_cast(int, acc0), off, 64));
        acc1 += __builtin_bit_cast(h2, __shfl_xor(__builtin_bit_cast(int, acc1), off, 64));
        acc2 += __builtin_bit_cast(h2, __shfl_xor(__builtin_bit_cast(int, acc2), off, 64));
        acc3 += __builtin_bit_cast(h2, __shfl_xor(__builtin_bit_cast(int, acc3), off, 64));
    }
    #pragma unroll
    for (int off = 4; off < 64; off <<= 1) zacc += __shfl_xor(zacc, off, 64);
    const float zz = __shfl(zacc, hh, 64);
    const float rz = QUNSCALE / (zz + 1e-16f);
    const h2 b0 = __builtin_bit_cast(h2, bv.x);
    const h2 b1 = __builtin_bit_cast(h2, bv.y);
    const h2 b2 = __builtin_bit_cast(h2, bv.z);
    const h2 b3 = __builtin_bit_cast(h2, bv.w);
    const float v0 = (float)acc0.x * rz + (float)b0.x;
    const float v1 = (float)acc0.y * rz + (float)b0.y;
    const float v2 = (float)acc1.x * rz + (float)b1.x;
    const float v3 = (float)acc1.y * rz + (float)b1.y;
    const float v4 = (float)acc2.x * rz + (float)b2.x;
    const float v5 = (float)acc2.y * rz + (float)b2.y;
    const float v6 = (float)acc3.x * rz + (float)b3.x;
    const float v7 = (float)acc3.y * rz + (float)b3.y;
    float s1 = v0 + v1 + v2 + v3 + v4 + v5 + v6 + v7;
    float s2 = v0 * v0 + v1 * v1 + v2 * v2 + v3 * v3
             + v4 * v4 + v5 * v5 + v6 * v6 + v7 * v7;
    #pragma unroll
    for (int off = 1; off < 16; off <<= 1) {
        s1 += __shfl_xor(s1, off, 64);
        s2 += __shfl_xor(s2, off, 64);
    }
    const float mu = s1 * (1.f / 128.f);
    const float var = s2 * (1.f / 128.f) - mu * mu;
    const float r = rsqrtf(var + 1e-5f);
    const float lo = grp == 0 ? v0 : grp == 1 ? v2 : grp == 2 ? v4 : v6;
    const float hi = grp == 0 ? v1 : grp == 1 ? v3 : grp == 2 ? v5 : v7;
    f32x2 o2;
    o2.x = (lo - mu) * r * g2.x + lb2.x;
    o2.y = (hi - mu) * r * g2.y + lb2.y;
    __builtin_nontemporal_store(o2, (f32x2*)out + ((size_t)i * 64 + l15 * 4 + grp));
}

extern "C" void kernel_launch(void* const* d_in, const int* in_sizes, int n_in,
                              void* d_out, int out_size, void* d_ws, size_t ws_size,
                              hipStream_t stream) {
    const float* x        = (const float*)d_in[0];
    const int*   ei       = (const int*)d_in[1];
    const float* W        = (const float*)d_in[2];
    const float* att_src  = (const float*)d_in[3];
    const float* att_dst  = (const float*)d_in[4];
    const float* gat_bias = (const float*)d_in[5];
    const float* skip_W   = (const float*)d_in[6];
    const float* skip_b   = (const float*)d_in[7];
    const float* ln_g     = (const float*)d_in[8];
    const float* ln_b     = (const float*)d_in[9];
    float* out = (float*)d_out;

    const int n  = in_sizes[0] / D;   // 100000
    const int E_ = in_sizes[1] / 2;   // 1600000
    const int nb = (n + 255) >> 8;

    char* p = (char*)d_ws;
    auto carve = [&p](size_t bytes) {
        char* r = p;
        p += (bytes + 255) & ~(size_t)255;
        return r;
    };
    short* wsT            = (short*)carve(32768 * sizeof(short));
    unsigned short* hb    = (unsigned short*)carve((size_t)n * D * 2);
    unsigned short* baseb = (unsigned short*)carve((size_t)n * D * 2);
    float* a_s            = (float*)carve((size_t)n * HEADS * 4);
    float* a_d            = (float*)carve((size_t)n * HEADS * 4);
    int*   cnt            = (int*)carve((size_t)n * 4);
    int*   offs           = (int*)carve((size_t)n * 4);
    int*   woffA          = (int*)carve(512 * 4);
    int*   ssrc           = (int*)carve((size_t)nb * BCAP * 4);
    unsigned int* pairs   = (unsigned int*)carve((size_t)nb * BCAP * 4);

    wprep_kernel<<<128, 256, 0, stream>>>(W, skip_W, wsT, woffA, nb);
    gemm_mfma_kernel<<<(n + 63) / 64, 512, 0, stream>>>(x, wsT, skip_b, gat_bias,
                                                        att_src, att_dst,
                                                        hb, baseb, a_s, a_d, n);
    const int BA = (E_ + BCHUNK - 1) / BCHUNK;
    binA_kernel<<<BA, 256, 0, stream>>>(ei, woffA, pairs, E_, nb);
    binB_kernel<<<nb, 256, 0, stream>>>(pairs, woffA, cnt, offs, ssrc, n);
    gather_kernel<<<(n + 3) / 4, 256, 0, stream>>>(offs, cnt, ssrc, a_s, a_d,
                                                   (const uint4*)hb,
                                                   (const uint4*)baseb,
                                                   ln_g, ln_b, out, n);
}

// Round 6
// 270.705 us; speedup vs baseline: 1.0507x; 1.0409x over previous
//
#include <hip/hip_runtime.h>
#include <hip/hip_bf16.h>

#define D 128
#define HEADS 4
#define NEG_SLOPE 0.2f
#define QSCALE 0.0625f
#define QUNSCALE 16.0f

// 64-node buckets: mean load 1024, sigma ~32; cap = mean + 8 sigma
#define BCAP64 1280
#define NB_HIST 1600
#define BEPT 16
#define BCHUNK (256 * BEPT)
#define WPREP_BLOCKS 128
#define LDSPAD 136

typedef __attribute__((ext_vector_type(8))) short short8;
typedef __attribute__((ext_vector_type(4))) float f32x4;
typedef __attribute__((ext_vector_type(2))) float f32x2;
typedef __attribute__((ext_vector_type(2))) _Float16 h2;

__device__ __forceinline__ float lrelu(float v) {
    return fmaxf(v, NEG_SLOPE * v);   // valid since NEG_SLOPE < 1
}

__device__ __forceinline__ short f2bf(float v) {
    __hip_bfloat16 b = __float2bfloat16(v);
    short s;
    __builtin_memcpy(&s, &b, 2);
    return s;
}

__device__ __forceinline__ unsigned short f2h(float v) {
    _Float16 h = (_Float16)v;
    unsigned short s;
    __builtin_memcpy(&s, &h, 2);
    return s;
}

// ===== Launch 1: binA (blocks [0,BA)) fused with wprep (blocks [BA,BA+128)) =
// pairs packed 32-bit: (src << 6) | (dst & 63); bucket = dst >> 6.
// woffA holds bucket-RELATIVE cursors (zeroed by memsetAsync).
__global__ __launch_bounds__(256)
void prep_kernel(const float* __restrict__ W, const float* __restrict__ S,
                 short* __restrict__ wsT,
                 const int* __restrict__ ei, int* __restrict__ woffA,
                 unsigned int* __restrict__ pairs, int E_, int nb64, int BA) {
    const int t = threadIdx.x;
    if ((int)blockIdx.x >= BA) {
        // ---- wprep: combined [W | skip_W] -> bf16 transposed wsT[256][128]
        const int idx = (blockIdx.x - BA) * 256 + t;     // 0..32767
        const int nn = idx >> 7, k = idx & 127;
        const float v = (nn < 128) ? W[k * D + nn] : S[k * D + (nn - 128)];
        wsT[idx] = f2bf(v);
        return;
    }
    // ---- binA: histogram + chunk-grab + direct scatter into 64-node buckets
    __shared__ int hist[NB_HIST];
    __shared__ int gbase[NB_HIST];
    for (int q = t; q < nb64; q += 256) hist[q] = 0;
    __syncthreads();
    int sv[BEPT], dv[BEPT], rk[BEPT];
    const int base = blockIdx.x * BCHUNK;
    #pragma unroll
    for (int i = 0; i < BEPT; ++i) {
        const int e = base + i * 256 + t;
        if (e < E_) {
            sv[i] = ei[e];
            dv[i] = ei[E_ + e];
            rk[i] = atomicAdd(&hist[dv[i] >> 6], 1);
        } else {
            sv[i] = -1;
        }
    }
    __syncthreads();
    for (int q = t; q < nb64; q += 256) {
        const int v = hist[q];
        gbase[q] = v ? (q * BCAP64 + atomicAdd(&woffA[q], v)) : 0;
    }
    __syncthreads();
    #pragma unroll
    for (int i = 0; i < BEPT; ++i) {
        if (sv[i] >= 0) {
            const int q = dv[i] >> 6;
            const unsigned int pos = (unsigned int)(gbase[q] + rk[i]);
            if (pos < (unsigned int)(q + 1) * BCAP64)
                pairs[pos] = ((unsigned int)sv[i] << 6) | (unsigned int)(dv[i] & 63);
        }
    }
}

// ===== Launch 2: binB (blocks [0,nbbB)) fused with MFMA gemm ================
__global__ __launch_bounds__(512, 4)
void mid_kernel(const float* __restrict__ x, const short* __restrict__ wsT,
                const float* __restrict__ skip_b, const float* __restrict__ gat_bias,
                const float* __restrict__ att_src, const float* __restrict__ att_dst,
                unsigned short* __restrict__ hb, unsigned short* __restrict__ baseb,
                float* __restrict__ a_s, float* __restrict__ a_d,
                const unsigned int* __restrict__ pairs, const int* __restrict__ wcur,
                int* __restrict__ cnt, int* __restrict__ offs, int* __restrict__ ssrc,
                int n, int nb64, int nbbB) {
    __shared__ __align__(16) char smem[64 * LDSPAD * 2];   // 17408 B
    const int t = threadIdx.x;
    if ((int)blockIdx.x < nbbB) {
        // ---- binB: two 64-node buckets per 512-thread block ----
        int* lds = (int*)smem;
        const int sub = t >> 8, tt = t & 255;
        int* nh = lds + sub * 160;         // [64] per-node hist / local base
        int* sc = lds + sub * 160 + 80;    // [64] scan buffer
        const int qb = blockIdx.x * 2 + sub;
        const bool valid = qb < nb64;
        const int sbeg = valid ? qb * BCAP64 : 0;
        int total = valid ? wcur[qb] : 0;
        if (total > BCAP64) total = BCAP64;
        const int send = sbeg + total;
        if (tt < 64) nh[tt] = 0;
        __syncthreads();
        unsigned int pk[6];
        int rk[6];
        int nl = 0;
        #pragma unroll
        for (int r = 0; r < 5; ++r) {
            const int e = sbeg + r * 256 + tt;
            if (e < send) {
                const unsigned int p = pairs[e];
                const int rr = atomicAdd(&nh[p & 63], 1);
                pk[nl] = p; rk[nl] = rr; ++nl;
            }
        }
        __syncthreads();
        const int v = (tt < 64) ? nh[tt] : 0;
        if (tt < 64) sc[tt] = v;
        __syncthreads();
        for (int off = 1; off < 64; off <<= 1) {
            const int xv = (tt >= off && tt < 64) ? sc[tt - off] : 0;
            __syncthreads();
            if (tt < 64) sc[tt] += xv;
            __syncthreads();
        }
        const int ex = (tt < 64) ? sc[tt] - v : 0;
        if (tt < 64 && valid) {
            const int node = qb * 64 + tt;
            if (node < n) { cnt[node] = v; offs[node] = sbeg + ex; }
        }
        __syncthreads();
        if (tt < 64) nh[tt] = ex;
        __syncthreads();
        for (int i = 0; i < nl; ++i)
            ssrc[sbeg + nh[pk[i] & 63] + rk[i]] = (int)(pk[i] >> 6);
        return;
    }
    // ---- gemm: 64 rows x 256 combined cols, 8 waves of 32x64 ----
    short (*xs)[LDSPAD] = (short(*)[LDSPAD])smem;
    const int row0 = (blockIdx.x - nbbB) * 64;
    #pragma unroll
    for (int i = 0; i < 4; ++i) {
        const int f = t + 512 * i;                 // 0..2047
        const int row = f >> 5, c4 = (f & 31) * 4;
        float4 v = make_float4(0.f, 0.f, 0.f, 0.f);
        if (row0 + row < n) v = *(const float4*)&x[(size_t)(row0 + row) * D + c4];
        short4 s4;
        s4.x = f2bf(v.x); s4.y = f2bf(v.y); s4.z = f2bf(v.z); s4.w = f2bf(v.w);
        *(short4*)&xs[row][c4] = s4;
    }
    __syncthreads();
    const int wv = t >> 6, lane = t & 63;
    const int lo = lane & 15, hi = lane >> 4;
    const int wr = wv >> 2;
    const int wc = wv & 3;
    f32x4 acc[2][4] = {};
    #pragma unroll
    for (int k0 = 0; k0 < 128; k0 += 32) {
        const int kk = k0 + hi * 8;
        short8 a0 = *(const short8*)&xs[wr * 32 + lo][kk];
        short8 a1 = *(const short8*)&xs[wr * 32 + 16 + lo][kk];
        #pragma unroll
        for (int nt = 0; nt < 4; ++nt) {
            short8 b = *(const short8*)&wsT[(wc * 64 + nt * 16 + lo) * D + kk];
            acc[0][nt] = __builtin_amdgcn_mfma_f32_16x16x32_bf16(a0, b, acc[0][nt], 0, 0, 0);
            acc[1][nt] = __builtin_amdgcn_mfma_f32_16x16x32_bf16(a1, b, acc[1][nt], 0, 0, 0);
        }
    }
    // fused a_s/a_d for the H half (cols 0..127): head = col>>5
    if (wc < 2) {
        float as_[4], ad_[4];
        #pragma unroll
        for (int nt = 0; nt < 4; ++nt) {
            const int c = wc * 64 + nt * 16 + lo;
            as_[nt] = att_src[c];
            ad_[nt] = att_dst[c];
        }
        #pragma unroll
        for (int mt = 0; mt < 2; ++mt) {
            #pragma unroll
            for (int reg = 0; reg < 4; ++reg) {
                float ps0 = acc[mt][0][reg] * as_[0] + acc[mt][1][reg] * as_[1];
                float ps1 = acc[mt][2][reg] * as_[2] + acc[mt][3][reg] * as_[3];
                float pd0 = acc[mt][0][reg] * ad_[0] + acc[mt][1][reg] * ad_[1];
                float pd1 = acc[mt][2][reg] * ad_[2] + acc[mt][3][reg] * ad_[3];
                #pragma unroll
                for (int off = 1; off < 16; off <<= 1) {
                    ps0 += __shfl_xor(ps0, off, 64);
                    ps1 += __shfl_xor(ps1, off, 64);
                    pd0 += __shfl_xor(pd0, off, 64);
                    pd1 += __shfl_xor(pd1, off, 64);
                }
                if (lo == 0) {
                    const int r = row0 + wr * 32 + mt * 16 + hi * 4 + reg;
                    if (r < n) {
                        a_s[r * HEADS + wc * 2 + 0] = ps0;
                        a_s[r * HEADS + wc * 2 + 1] = ps1;
                        a_d[r * HEADS + wc * 2 + 0] = pd0;
                        a_d[r * HEADS + wc * 2 + 1] = pd1;
                    }
                }
            }
        }
    }
    // epilogue: C/D layout col=lane&15, row=(lane>>4)*4+reg  (stores FP16)
    #pragma unroll
    for (int nt = 0; nt < 4; ++nt) {
        const int cc = wc * 64 + nt * 16 + lo;
        const bool isH = cc < 128;
        const float bb = isH ? 0.f : (skip_b[cc - 128] + gat_bias[cc - 128]);
        unsigned short* dst = isH ? hb : baseb;
        const int c = isH ? cc : cc - 128;
        #pragma unroll
        for (int mt = 0; mt < 2; ++mt) {
            const int rbase = row0 + wr * 32 + mt * 16 + hi * 4;
            #pragma unroll
            for (int reg = 0; reg < 4; ++reg) {
                const int r = rbase + reg;
                if (r < n) dst[(size_t)r * D + c] = f2h(acc[mt][nt][reg] + bb);
            }
        }
    }
}

// ---------------- Gather: wave/node; 16 lanes/edge, uint4 rows --------------
__global__ __launch_bounds__(256)
void gather_kernel(const int* __restrict__ offs, const int* __restrict__ cnt,
                   const int* __restrict__ ssrc, const float* __restrict__ a_s,
                   const float* __restrict__ a_d, const uint4* __restrict__ hb16,
                   const uint4* __restrict__ baseb16,
                   const float* __restrict__ ln_g, const float* __restrict__ ln_b,
                   float* __restrict__ out, int n) {
    const int lane = threadIdx.x & 63;
    const int i = blockIdx.x * 4 + (threadIdx.x >> 6);
    if (i >= n) return;
    const int e4 = lane >> 2, h4 = lane & 3;
    const int l15 = lane & 15;
    const int grp = lane >> 4;
    const int hh = l15 >> 2;              // head of this lane's 8 channels
    // prefetch tail operands off the critical path
    const uint4 bv = baseb16[(size_t)i * 16 + l15];
    const float2 g2 = ((const float2*)ln_g)[l15 * 4 + grp];
    const float2 lb2 = ((const float2*)ln_b)[l15 * 4 + grp];
    const float as_h4 = a_s[i * HEADS + h4];
    const float ad_h4 = a_d[i * HEADS + h4];
    const float qself = __expf(lrelu(as_h4 + ad_h4));
    float zacc = (e4 == 0) ? qself : 0.f;
    h2 acc0 = {0.f, 0.f}, acc1 = {0.f, 0.f}, acc2 = {0.f, 0.f}, acc3 = {0.f, 0.f};
    {
        const float qs = __shfl(qself, hh, 64) * QSCALE;
        if (grp == 0) {
            const uint4 u = hb16[(size_t)i * 16 + l15];
            const _Float16 wh = (_Float16)qs;
            const h2 w2 = {wh, wh};
            acc0 = __builtin_bit_cast(h2, u.x) * w2;
            acc1 = __builtin_bit_cast(h2, u.y) * w2;
            acc2 = __builtin_bit_cast(h2, u.z) * w2;
            acc3 = __builtin_bit_cast(h2, u.w) * w2;
        }
    }
    const int o = offs[i];
    const int c = cnt[i];
    for (int k0 = 0; k0 < c; k0 += 16) {
        const int rem = c - k0;
        int srow = 0;
        float q = 0.f;
        if (e4 < rem) {
            const int sidx = ssrc[o + k0 + e4];
            srow = sidx << 4;
            q = __expf(lrelu(a_s[sidx * HEADS + h4] + ad_h4));
        }
        zacc += q;
        const _Float16 qh = (_Float16)(q * QSCALE);
        const h2 qv = {qh, qh};
        const int qpk = __builtin_bit_cast(int, qv);
        const int m = rem < 16 ? rem : 16;
        int ee = 0;
        for (; ee + 8 <= m; ee += 8) {
            const int slA = (ee + grp) << 2;
            const int slB = (ee + 4 + grp) << 2;
            const int rA = __shfl(srow, slA, 64) + l15;
            const int rB = __shfl(srow, slB, 64) + l15;
            const h2 qA = __builtin_bit_cast(h2, __shfl(qpk, slA + hh, 64));
            const h2 qB = __builtin_bit_cast(h2, __shfl(qpk, slB + hh, 64));
            const uint4 uA = hb16[(size_t)(unsigned)rA];
            const uint4 uB = hb16[(size_t)(unsigned)rB];
            acc0 += __builtin_bit_cast(h2, uA.x) * qA;
            acc1 += __builtin_bit_cast(h2, uA.y) * qA;
            acc2 += __builtin_bit_cast(h2, uA.z) * qA;
            acc3 += __builtin_bit_cast(h2, uA.w) * qA;
            acc0 += __builtin_bit_cast(h2, uB.x) * qB;
            acc1 += __builtin_bit_cast(h2, uB.y) * qB;
            acc2 += __builtin_bit_cast(h2, uB.z) * qB;
            acc3 += __builtin_bit_cast(h2, uB.w) * qB;
        }
        for (; ee < m; ee += 4) {
            const int slot = ee + grp;
            const int sl = slot << 2;
            const int rA = __shfl(srow, sl, 64) + l15;
            const h2 qA = __builtin_bit_cast(h2, __shfl(qpk, sl + hh, 64));
            if (slot < m) {
                const uint4 uA = hb16[(size_t)(unsigned)rA];
                acc0 += __builtin_bit_cast(h2, uA.x) * qA;
                acc1 += __builtin_bit_cast(h2, uA.y) * qA;
                acc2 += __builtin_bit_cast(h2, uA.z) * qA;
                acc3 += __builtin_bit_cast(h2, uA.w) * qA;
            }
        }
    }
    // merge the 4 edge-slot groups (packed fp16 adds)
    #pragma unroll
    for (int off = 16; off < 64; off <<= 1) {
        acc0 += __builtin_bit_cast(h2, __shfl_xor(__builtin_bit_cast(int, acc0), off, 64));
        acc1 += __builtin_bit_cast(h2, __shfl_xor(__builtin_bit_cast(int, acc1), off, 64));
        acc2 += __builtin_bit_cast(h2, __shfl_xor(__builtin_bit_cast(int, acc2), off, 64));
        acc3 += __builtin_bit_cast(h2, __shfl_xor(__builtin_bit_cast(int, acc3), off, 64));
    }
    #pragma unroll
    for (int off = 4; off < 64; off <<= 1) zacc += __shfl_xor(zacc, off, 64);
    const float zz = __shfl(zacc, hh, 64);
    const float rz = QUNSCALE / (zz + 1e-16f);
    const h2 b0 = __builtin_bit_cast(h2, bv.x);
    const h2 b1 = __builtin_bit_cast(h2, bv.y);
    const h2 b2 = __builtin_bit_cast(h2, bv.z);
    const h2 b3 = __builtin_bit_cast(h2, bv.w);
    const float v0 = (float)acc0.x * rz + (float)b0.x;
    const float v1 = (float)acc0.y * rz + (float)b0.y;
    const float v2 = (float)acc1.x * rz + (float)b1.x;
    const float v3 = (float)acc1.y * rz + (float)b1.y;
    const float v4 = (float)acc2.x * rz + (float)b2.x;
    const float v5 = (float)acc2.y * rz + (float)b2.y;
    const float v6 = (float)acc3.x * rz + (float)b3.x;
    const float v7 = (float)acc3.y * rz + (float)b3.y;
    float s1 = v0 + v1 + v2 + v3 + v4 + v5 + v6 + v7;
    float s2 = v0 * v0 + v1 * v1 + v2 * v2 + v3 * v3
             + v4 * v4 + v5 * v5 + v6 * v6 + v7 * v7;
    #pragma unroll
    for (int off = 1; off < 16; off <<= 1) {
        s1 += __shfl_xor(s1, off, 64);
        s2 += __shfl_xor(s2, off, 64);
    }
    const float mu = s1 * (1.f / 128.f);
    const float var = s2 * (1.f / 128.f) - mu * mu;
    const float r = rsqrtf(var + 1e-5f);
    const float lo = grp == 0 ? v0 : grp == 1 ? v2 : grp == 2 ? v4 : v6;
    const float hi = grp == 0 ? v1 : grp == 1 ? v3 : grp == 2 ? v5 : v7;
    f32x2 o2;
    o2.x = (lo - mu) * r * g2.x + lb2.x;
    o2.y = (hi - mu) * r * g2.y + lb2.y;
    __builtin_nontemporal_store(o2, (f32x2*)out + ((size_t)i * 64 + l15 * 4 + grp));
}

extern "C" void kernel_launch(void* const* d_in, const int* in_sizes, int n_in,
                              void* d_out, int out_size, void* d_ws, size_t ws_size,
                              hipStream_t stream) {
    const float* x        = (const float*)d_in[0];
    const int*   ei       = (const int*)d_in[1];
    const float* W        = (const float*)d_in[2];
    const float* att_src  = (const float*)d_in[3];
    const float* att_dst  = (const float*)d_in[4];
    const float* gat_bias = (const float*)d_in[5];
    const float* skip_W   = (const float*)d_in[6];
    const float* skip_b   = (const float*)d_in[7];
    const float* ln_g     = (const float*)d_in[8];
    const float* ln_b     = (const float*)d_in[9];
    float* out = (float*)d_out;

    const int n    = in_sizes[0] / D;   // 100000
    const int E_   = in_sizes[1] / 2;   // 1600000
    const int nb64 = (n + 63) >> 6;     // 1563 buckets of 64 nodes
    const int nbbB = (nb64 + 1) >> 1;   // 782 binB blocks (2 buckets each)

    char* p = (char*)d_ws;
    auto carve = [&p](size_t bytes) {
        char* r = p;
        p += (bytes + 255) & ~(size_t)255;
        return r;
    };
    short* wsT            = (short*)carve(32768 * sizeof(short));
    unsigned short* hb    = (unsigned short*)carve((size_t)n * D * 2);
    unsigned short* baseb = (unsigned short*)carve((size_t)n * D * 2);
    float* a_s            = (float*)carve((size_t)n * HEADS * 4);
    float* a_d            = (float*)carve((size_t)n * HEADS * 4);
    int*   cnt            = (int*)carve((size_t)n * 4);
    int*   offs           = (int*)carve((size_t)n * 4);
    int*   woffA          = (int*)carve((size_t)nb64 * 4);
    int*   ssrc           = (int*)carve((size_t)nb64 * BCAP64 * 4);
    unsigned int* pairs   = (unsigned int*)carve((size_t)nb64 * BCAP64 * 4);

    hipMemsetAsync(woffA, 0, (size_t)nb64 * 4, stream);

    const int BA = (E_ + BCHUNK - 1) / BCHUNK;          // 391
    prep_kernel<<<BA + WPREP_BLOCKS, 256, 0, stream>>>(W, skip_W, wsT, ei, woffA,
                                                       pairs, E_, nb64, BA);
    const int ngemm = (n + 63) / 64;                     // 1563
    mid_kernel<<<nbbB + ngemm, 512, 0, stream>>>(x, wsT, skip_b, gat_bias,
                                                 att_src, att_dst,
                                                 hb, baseb, a_s, a_d,
                                                 pairs, woffA,
                                                 cnt, offs, ssrc, n, nb64, nbbB);
    gather_kernel<<<(n + 3) / 4, 256, 0, stream>>>(offs, cnt, ssrc, a_s, a_d,
                                                   (const uint4*)hb,
                                                   (const uint4*)baseb,
                                                   ln_g, ln_b, out, n);
}